// Round 17
// baseline (632.568 us; speedup 1.0000x reference)
//
#include <hip/hip_runtime.h>

// ---------------------------------------------------------------------------
// E-GraphSAGE forward. Stages:
//   1. CSR build by dst (histogram + scan + fill -> (edge,src) pairs + dsts)
//   2. agg1 [N,80]  = sums of [x[src](16) | ea(64)] per dst  (single ea pass)
//   3. h1  [N,128]  = ReLU([x | agg1/deg] @ W1 + b1)  (+ h1b bf16 copy)
//   4. agg2 [N,128] = sums of h1b[src] per dst (bf16 gather, f32 accum)
//   5. h2b [N,128]  = ReLU([h1 | agg2/deg | agg1_ea/deg] @ W2 + b2) -> bf16
//   6. out [E,1]    = edge MLP 320->128->64->1, bf16 MFMA, persistent blocks,
//                     processed in CSR order (dst rows L1-cached; -33% random
//                     gather lines), 512 thr / 32 edges per wave
// ---------------------------------------------------------------------------

#define SCAN_T 1024

typedef __attribute__((ext_vector_type(8))) short bf16x8;
typedef __attribute__((ext_vector_type(4))) float f32x4;

__device__ __forceinline__ unsigned short f2b(float f) {   // f32 -> bf16 RNE
    unsigned int u = __builtin_bit_cast(unsigned int, f);
    u += 0x7fffu + ((u >> 16) & 1u);
    return (unsigned short)(u >> 16);
}

__device__ __forceinline__ bf16x8 packbf(float4 a, float4 b) {
    bf16x8 p;
    p[0] = (short)f2b(a.x); p[1] = (short)f2b(a.y);
    p[2] = (short)f2b(a.z); p[3] = (short)f2b(a.w);
    p[4] = (short)f2b(b.x); p[5] = (short)f2b(b.y);
    p[6] = (short)f2b(b.z); p[7] = (short)f2b(b.w);
    return p;
}

// edge_index may arrive as int32 or int64 depending on harness conversion.
__device__ __forceinline__ int ld_idx(const void* ei, long long pos, int is64) {
    if (is64) return (int)((const long long*)ei)[pos];
    return ((const int*)ei)[pos];
}

__global__ void detect64_kernel(const void* ei, int* flag) {
    if (threadIdx.x == 0 && blockIdx.x == 0) {
        const int* p = (const int*)ei;
        int is64 = 1;
        for (int i = 0; i < 64; ++i) {
            if (p[2 * i + 1] != 0) { is64 = 0; break; }
        }
        *flag = is64;
    }
}

// Wc1[320][128] -> WT1[128][320] bf16 ; Wc2[128][64] -> WT2[64][128] bf16
__global__ void prep_w_kernel(const float* __restrict__ Wc1,
                              const float* __restrict__ Wc2,
                              unsigned short* __restrict__ WT1,
                              unsigned short* __restrict__ WT2) {
    int i = blockIdx.x * 256 + threadIdx.x;
    if (i < 320 * 128) { int k = i >> 7, n = i & 127; WT1[n * 320 + k] = f2b(Wc1[i]); }
    if (i < 128 * 64)  { int k = i >> 6, n = i & 63;  WT2[n * 128 + k] = f2b(Wc2[i]); }
}

__global__ void hist_kernel(const void* ei, int E, int* cnt, const int* flag) {
    int is64 = *flag;
    for (int e = blockIdx.x * blockDim.x + threadIdx.x; e < E;
         e += gridDim.x * blockDim.x) {
        int d = ld_idx(ei, (long long)E + e, is64);
        atomicAdd(&cnt[d], 1);
    }
}

__global__ void scan_kernel(const int* cnt, int* row, int n) {
    __shared__ int ps[SCAN_T];
    int tid = threadIdx.x;
    int per = (n + SCAN_T - 1) / SCAN_T;
    int s0 = tid * per;
    int s1 = min(s0 + per, n);
    int s = 0;
    for (int i = s0; i < s1; ++i) s += cnt[i];
    ps[tid] = s;
    __syncthreads();
    for (int off = 1; off < SCAN_T; off <<= 1) {
        int v = (tid >= off) ? ps[tid - off] : 0;
        __syncthreads();
        ps[tid] += v;
        __syncthreads();
    }
    int run = (tid == 0) ? 0 : ps[tid - 1];
    for (int i = s0; i < s1; ++i) { row[i] = run; run += cnt[i]; }
    if (s0 < n && s1 == n) row[n] = run;
}

// CSR fill storing (edge, src) pairs + dst per position.
__global__ void fill_kernel(const void* ei, int E, const int* row, int* cursor,
                            int2* epairs, int* dsts, const int* flag) {
    int is64 = *flag;
    for (int e = blockIdx.x * blockDim.x + threadIdx.x; e < E;
         e += gridDim.x * blockDim.x) {
        int d = ld_idx(ei, (long long)E + e, is64);
        int s = ld_idx(ei, e, is64);
        int pos = atomicAdd(&cursor[d], 1);
        epairs[row[d] + pos] = make_int2(e, s);
        dsts[row[d] + pos] = d;
    }
}

// agg1[node] = [sum x[src] (16) | sum ea (64)]; one wave/node, unroll-4.
__global__ void agg1_kernel(const int2* __restrict__ ep,
                            const float* __restrict__ x,
                            const float* __restrict__ ea,
                            const int* __restrict__ row,
                            float* __restrict__ agg1, int N) {
    int node = blockIdx.x * 4 + (threadIdx.x >> 6);
    int lane = threadIdx.x & 63;
    if (node >= N) return;
    int r0 = row[node], r1 = row[node + 1];
    float s0 = 0.f, s1 = 0.f, s2 = 0.f, s3 = 0.f, xs = 0.f;
    int i = r0;
    for (; i + 4 <= r1; i += 4) {
        int2 p0 = ep[i], p1 = ep[i + 1], p2 = ep[i + 2], p3 = ep[i + 3];
        float e0 = ea[(size_t)p0.x * 64 + lane];
        float e1 = ea[(size_t)p1.x * 64 + lane];
        float e2 = ea[(size_t)p2.x * 64 + lane];
        float e3 = ea[(size_t)p3.x * 64 + lane];
        if (lane < 16)
            xs += x[p0.y * 16 + lane] + x[p1.y * 16 + lane] +
                  x[p2.y * 16 + lane] + x[p3.y * 16 + lane];
        s0 += e0; s1 += e1; s2 += e2; s3 += e3;
    }
    for (; i < r1; ++i) {
        int2 p = ep[i];
        s0 += ea[(size_t)p.x * 64 + lane];
        if (lane < 16) xs += x[p.y * 16 + lane];
    }
    agg1[node * 80 + 16 + lane] = s0 + s1 + s2 + s3;
    if (lane < 16) agg1[node * 80 + lane] = xs;
}

// h1 (f32, for update2 self path) + h1b (bf16, for agg2 gather).
__global__ void update1_kernel(const float* __restrict__ x,
                               const float* __restrict__ agg1, const int* row,
                               const float* __restrict__ W1,
                               const float* __restrict__ b1,
                               float* __restrict__ h1,
                               unsigned short* __restrict__ h1b, int N) {
    __shared__ float in_s[8][96];
    int base = blockIdx.x * 8;
    int tid = threadIdx.x;
    for (int idx = tid; idx < 8 * 96; idx += 128) {
        int i = idx / 96, k = idx % 96;
        int node = base + i;
        float v = 0.f;
        if (node < N) {
            if (k < 16) v = x[node * 16 + k];
            else {
                float inv = 1.f / fmaxf((float)(row[node + 1] - row[node]), 1.f);
                v = agg1[node * 80 + (k - 16)] * inv;
            }
        }
        in_s[i][k] = v;
    }
    __syncthreads();
    int j = tid;
    float acc[8];
#pragma unroll
    for (int i = 0; i < 8; ++i) acc[i] = 0.f;
    for (int k = 0; k < 96; ++k) {
        float w = W1[k * 128 + j];
#pragma unroll
        for (int i = 0; i < 8; ++i) acc[i] += in_s[i][k] * w;
    }
    float bj = b1[j];
#pragma unroll
    for (int i = 0; i < 8; ++i) {
        int node = base + i;
        if (node < N) {
            float v = fmaxf(acc[i] + bj, 0.f);
            h1[node * 128 + j] = v;
            h1b[node * 128 + j] = f2b(v);
        }
    }
}

// agg2[node] = sum h1b[src] (128 cols, bf16 gather, f32 accum). Lane covers
// cols {2*lane, 2*lane+1} via one uint load per edge. Unroll-4.
__global__ void agg2_kernel(const int2* __restrict__ ep,
                            const unsigned int* __restrict__ h1b32,
                            const int* __restrict__ row,
                            float* __restrict__ agg2, int N) {
    int node = blockIdx.x * 4 + (threadIdx.x >> 6);
    int lane = threadIdx.x & 63;
    if (node >= N) return;
    int r0 = row[node], r1 = row[node + 1];
    float a0 = 0.f, a1 = 0.f, a2 = 0.f, a3 = 0.f;   // col 2*lane
    float b0 = 0.f, b1 = 0.f, b2 = 0.f, b3 = 0.f;   // col 2*lane+1
    int i = r0;
    for (; i + 4 <= r1; i += 4) {
        unsigned int u0 = h1b32[(size_t)ep[i].y     * 64 + lane];
        unsigned int u1 = h1b32[(size_t)ep[i + 1].y * 64 + lane];
        unsigned int u2 = h1b32[(size_t)ep[i + 2].y * 64 + lane];
        unsigned int u3 = h1b32[(size_t)ep[i + 3].y * 64 + lane];
        a0 += __builtin_bit_cast(float, u0 << 16);
        b0 += __builtin_bit_cast(float, u0 & 0xffff0000u);
        a1 += __builtin_bit_cast(float, u1 << 16);
        b1 += __builtin_bit_cast(float, u1 & 0xffff0000u);
        a2 += __builtin_bit_cast(float, u2 << 16);
        b2 += __builtin_bit_cast(float, u2 & 0xffff0000u);
        a3 += __builtin_bit_cast(float, u3 << 16);
        b3 += __builtin_bit_cast(float, u3 & 0xffff0000u);
    }
    for (; i < r1; ++i) {
        unsigned int u = h1b32[(size_t)ep[i].y * 64 + lane];
        a0 += __builtin_bit_cast(float, u << 16);
        b0 += __builtin_bit_cast(float, u & 0xffff0000u);
    }
    agg2[node * 128 + 2 * lane]     = a0 + a1 + a2 + a3;
    agg2[node * 128 + 2 * lane + 1] = b0 + b1 + b2 + b3;
}

// h2 written as bf16; ea-mean slice read from agg1.
__global__ void update2_kernel(const float* __restrict__ h1,
                               const float* __restrict__ agg2,
                               const float* __restrict__ agg1, const int* row,
                               const float* __restrict__ W2,
                               const float* __restrict__ b2,
                               unsigned short* __restrict__ h2b, int N) {
    __shared__ float in_s[8][320];
    int base = blockIdx.x * 8;
    int tid = threadIdx.x;
    for (int idx = tid; idx < 8 * 320; idx += 128) {
        int i = idx / 320, k = idx % 320;
        int node = base + i;
        float v = 0.f;
        if (node < N) {
            if (k < 128) v = h1[node * 128 + k];
            else {
                float inv = 1.f / fmaxf((float)(row[node + 1] - row[node]), 1.f);
                if (k < 256) v = agg2[node * 128 + (k - 128)] * inv;
                else         v = agg1[node * 80 + 16 + (k - 256)] * inv;
            }
        }
        in_s[i][k] = v;
    }
    __syncthreads();
    int j = tid;
    float acc[8];
#pragma unroll
    for (int i = 0; i < 8; ++i) acc[i] = 0.f;
    for (int k = 0; k < 320; ++k) {
        float w = W2[k * 128 + j];
#pragma unroll
        for (int i = 0; i < 8; ++i) acc[i] += in_s[i][k] * w;
    }
    float bj = b2[j];
#pragma unroll
    for (int i = 0; i < 8; ++i) {
        int node = base + i;
        if (node < N) h2b[node * 128 + j] = f2b(fmaxf(acc[i] + bj, 0.f));
    }
}

// ---------------------------------------------------------------------------
// Persistent MFMA edge classifier in CSR ORDER. 512 threads (8 waves),
// 256-position tiles, 32 edges per wave. Consecutive CSR positions share dst
// -> h2b[dst] row gathers are L1 hits (cuts ~1/3 of random gather lines).
// Otherwise identical to the validated R16 structure.
// LDS = 81920 (Wc1 frags) + 68608 (z1b [256][134]) = 150528 B.
// ---------------------------------------------------------------------------
__global__ __launch_bounds__(512, 2) void classifier_mfma(
    const int2* __restrict__ epairs, const int* __restrict__ dsts,
    const unsigned short* __restrict__ h2b, const float* __restrict__ ea,
    const unsigned short* __restrict__ WT1, const float* __restrict__ bc1,
    const unsigned short* __restrict__ WT2, const float* __restrict__ bc2,
    const float* __restrict__ Wc3, const float* __restrict__ bc3,
    float* __restrict__ out, int E) {
    __shared__ __align__(16) char smem[150528];
    unsigned short* wt1f = (unsigned short*)smem;             // 40 frags x 128 j
    unsigned short* z1b  = (unsigned short*)(smem + 81920);   // [256][134]

    const int tid = threadIdx.x;
    const int l  = tid & 63;
    const int w  = tid >> 6;    // wave 0..7
    const int lm = l & 15;      // m/n index within 16x16 tile
    const int g  = l >> 4;      // k-group (frag k0 = 8*g)

    // ---- stage Wc1 frags once (frag-major) ----
    for (int i = tid; i < 5120; i += 512) {      // 40 frags x 128 j
        int f = i >> 7, j = i & 127;
        uint4 v = *(const uint4*)(WT1 + (size_t)j * 320 + (f >> 2) * 32 + (f & 3) * 8);
        *(uint4*)(wt1f + (size_t)i * 8) = v;
    }
    float wc3r[4];
#pragma unroll
    for (int n = 0; n < 4; ++n) wc3r[n] = Wc3[16 * n + lm];
    const float bc3s = bc3[0];
    const f32x4 zero = {0.f, 0.f, 0.f, 0.f};
    __syncthreads();   // weights visible; ONLY barrier

    const int T = (E + 255) / 256;
    for (int tile = blockIdx.x; tile < T; tile += gridDim.x) {
        const int tbase = tile * 256;

        // ---- gather A-frags for both edge-sets (CSR positions) ----
        bf16x8 A[2][10];
#pragma unroll
        for (int h = 0; h < 2; ++h) {
            const int p  = tbase + 32 * w + 16 * h + lm;
            const int pc = min(p, E - 1);
            const int2 pr = epairs[pc];
            const int dE = dsts[pc];
            const unsigned short* rs = h2b + (size_t)pr.y * 128 + g * 8;
            const unsigned short* rd = h2b + (size_t)dE * 128 + g * 8;
#pragma unroll
            for (int kt = 0; kt < 4; ++kt) A[h][kt] = *(const bf16x8*)(rs + kt * 32);
#pragma unroll
            for (int kt = 0; kt < 4; ++kt) A[h][4 + kt] = *(const bf16x8*)(rd + kt * 32);
            const float* pe = ea + (size_t)pr.x * 64 + g * 8;
            float4 f0 = *(const float4*)pe,        f1 = *(const float4*)(pe + 4);
            float4 f2 = *(const float4*)(pe + 32), f3 = *(const float4*)(pe + 36);
            A[h][8] = packbf(f0, f1);
            A[h][9] = packbf(f2, f3);
        }

        // ---- Phase A: K=320; one B read feeds 2 MFMAs ----
        f32x4 acc[2][8];
#pragma unroll
        for (int h = 0; h < 2; ++h)
#pragma unroll
            for (int n = 0; n < 8; ++n) acc[h][n] = zero;
#pragma unroll
        for (int kt = 0; kt < 10; ++kt) {
            const unsigned short* wb = wt1f + ((size_t)(kt * 4 + g) * 128) * 8;
#pragma unroll
            for (int n = 0; n < 8; ++n) {
                bf16x8 b = *(const bf16x8*)(wb + (size_t)(16 * n + lm) * 8);
                acc[0][n] = __builtin_amdgcn_mfma_f32_16x16x32_bf16(A[0][kt], b, acc[0][n], 0, 0, 0);
                acc[1][n] = __builtin_amdgcn_mfma_f32_16x16x32_bf16(A[1][kt], b, acc[1][n], 0, 0, 0);
            }
        }
        // epilogue A: bias+ReLU -> z1b rows 32w+16h+(4g+r)
#pragma unroll
        for (int n = 0; n < 8; ++n) {
            float bj = bc1[16 * n + lm];
#pragma unroll
            for (int h = 0; h < 2; ++h)
#pragma unroll
                for (int r = 0; r < 4; ++r) {
                    float v = fmaxf(acc[h][n][r] + bj, 0.f);
                    z1b[(size_t)(32 * w + 16 * h + g * 4 + r) * 134 + 16 * n + lm] = f2b(v);
                }
        }

        // ---- Phase B: K=128; one WT2 B read feeds 2 MFMAs ----
        f32x4 acc2[2][4];
#pragma unroll
        for (int h = 0; h < 2; ++h)
#pragma unroll
            for (int n = 0; n < 4; ++n) acc2[h][n] = zero;
        const unsigned short* brow0 = z1b + (size_t)(32 * w + lm) * 134;
        const unsigned short* brow1 = z1b + (size_t)(32 * w + 16 + lm) * 134;
#pragma unroll
        for (int kt = 0; kt < 4; ++kt) {
            bf16x8 a0 = *(const bf16x8*)(brow0 + kt * 32 + g * 8);
            bf16x8 a1 = *(const bf16x8*)(brow1 + kt * 32 + g * 8);
#pragma unroll
            for (int n = 0; n < 4; ++n) {
                bf16x8 b = *(const bf16x8*)(WT2 + (size_t)(16 * n + lm) * 128 + kt * 32 + g * 8);
                acc2[0][n] = __builtin_amdgcn_mfma_f32_16x16x32_bf16(a0, b, acc2[0][n], 0, 0, 0);
                acc2[1][n] = __builtin_amdgcn_mfma_f32_16x16x32_bf16(a1, b, acc2[1][n], 0, 0, 0);
            }
        }

        // ---- Phase C: bias+ReLU in regs, per-lane dot, shfl reduce,
        //      scatter to out[edge id] ----
#pragma unroll
        for (int h = 0; h < 2; ++h) {
            float p[4];
#pragma unroll
            for (int r = 0; r < 4; ++r) p[r] = 0.f;
#pragma unroll
            for (int n = 0; n < 4; ++n) {
                float bj = bc2[16 * n + lm];
#pragma unroll
                for (int r = 0; r < 4; ++r) {
                    float z = fmaxf(acc2[h][n][r] + bj, 0.f);
                    p[r] += z * wc3r[n];
                }
            }
#pragma unroll
            for (int r = 0; r < 4; ++r) {
                p[r] += __shfl_xor(p[r], 1, 16);
                p[r] += __shfl_xor(p[r], 2, 16);
                p[r] += __shfl_xor(p[r], 4, 16);
                p[r] += __shfl_xor(p[r], 8, 16);
            }
            if (lm == 0) {
#pragma unroll
                for (int r = 0; r < 4; ++r) {
                    int po = tbase + 32 * w + 16 * h + 4 * g + r;
                    if (po < E) out[epairs[po].x] = p[r] + bc3s;
                }
            }
        }
    }
}

extern "C" void kernel_launch(void* const* d_in, const int* in_sizes, int n_in,
                              void* d_out, int out_size, void* d_ws,
                              size_t ws_size, hipStream_t stream) {
    const float* x   = (const float*)d_in[0];
    const void*  ei  = d_in[1];
    const float* ea  = (const float*)d_in[2];
    const float* W1  = (const float*)d_in[3];
    const float* b1  = (const float*)d_in[4];
    const float* W2  = (const float*)d_in[5];
    const float* b2  = (const float*)d_in[6];
    const float* Wc1 = (const float*)d_in[7];
    const float* bc1 = (const float*)d_in[8];
    const float* Wc2 = (const float*)d_in[9];
    const float* bc2 = (const float*)d_in[10];
    const float* Wc3 = (const float*)d_in[11];
    const float* bc3 = (const float*)d_in[12];
    float* out = (float*)d_out;

    int N = in_sizes[0] / 16;   // 50000
    int E = in_sizes[2] / 64;   // 800000

    char* ws = (char*)d_ws;
    size_t off = 0;
    auto alloc = [&](size_t bytes) {
        void* p = ws + off;
        off += (bytes + 511) & ~(size_t)511;
        return p;
    };
    int*            cnt    = (int*)alloc((size_t)N * 4);
    int*            cursor = (int*)alloc((size_t)N * 4);
    int*            row    = (int*)alloc((size_t)(N + 1) * 4);
    int2*           epairs = (int2*)alloc((size_t)E * 8);
    int*            dsts   = (int*)alloc((size_t)E * 4);
    int*            flag   = (int*)alloc(4);
    float*          agg1   = (float*)alloc((size_t)N * 80 * 4);
    float*          h1     = (float*)alloc((size_t)N * 128 * 4);
    unsigned short* h1b    = (unsigned short*)alloc((size_t)N * 128 * 2);
    float*          agg2   = (float*)alloc((size_t)N * 128 * 4);
    unsigned short* h2b    = (unsigned short*)alloc((size_t)N * 128 * 2);
    unsigned short* WT1    = (unsigned short*)alloc((size_t)128 * 320 * 2);
    unsigned short* WT2    = (unsigned short*)alloc((size_t)64 * 128 * 2);
    (void)ws_size; (void)n_in; (void)out_size;

    hipMemsetAsync(cnt, 0, (size_t)N * 4, stream);
    hipMemsetAsync(cursor, 0, (size_t)N * 4, stream);

    detect64_kernel<<<1, 64, 0, stream>>>(ei, flag);
    prep_w_kernel<<<160, 256, 0, stream>>>(Wc1, Wc2, WT1, WT2);
    hist_kernel<<<1024, 256, 0, stream>>>(ei, E, cnt, flag);
    scan_kernel<<<1, SCAN_T, 0, stream>>>(cnt, row, N);
    fill_kernel<<<1024, 256, 0, stream>>>(ei, E, row, cursor, epairs, dsts, flag);
    agg1_kernel<<<(N + 3) / 4, 256, 0, stream>>>(epairs, x, ea, row, agg1, N);
    update1_kernel<<<(N + 7) / 8, 128, 0, stream>>>(x, agg1, row, W1, b1, h1, h1b, N);
    agg2_kernel<<<(N + 3) / 4, 256, 0, stream>>>(epairs, (const unsigned int*)h1b, row, agg2, N);
    update2_kernel<<<(N + 7) / 8, 128, 0, stream>>>(h1, agg2, agg1, row, W2, b2, h2b, N);
    classifier_mfma<<<256, 512, 0, stream>>>(epairs, dsts, h2b, ea, WT1, bc1,
                                             WT2, bc2, Wc3, bc3, out, E);
}

// Round 18
// 405.595 us; speedup vs baseline: 1.5596x; 1.5596x over previous
//
#include <hip/hip_runtime.h>

// ---------------------------------------------------------------------------
// E-GraphSAGE forward. Stages:
//   1. CSR build by dst (histogram + multi-block scan + fill -> (edge,src))
//   2. agg1 [N,80]  = sums of [x[src](16) | ea(64)] per dst
//   3. h1b [N,128]  = ReLU([x | agg1/deg] @ W1 + b1) -> bf16
//   4. agg2 [N,128] = sums of h1b[src] per dst (bf16 gather, f32 accum)
//   5. h2b [N,128]  = ReLU([h1b | agg2/deg | agg1_ea/deg] @ W2 + b2), MFMA
//   6. out [E,1]    = edge MLP 320->128->64->1, bf16 MFMA (R16 structure)
// ---------------------------------------------------------------------------

typedef __attribute__((ext_vector_type(8))) short bf16x8;
typedef __attribute__((ext_vector_type(4))) float f32x4;

__device__ __forceinline__ unsigned short f2b(float f) {   // f32 -> bf16 RNE
    unsigned int u = __builtin_bit_cast(unsigned int, f);
    u += 0x7fffu + ((u >> 16) & 1u);
    return (unsigned short)(u >> 16);
}

__device__ __forceinline__ bf16x8 packbf(float4 a, float4 b) {
    bf16x8 p;
    p[0] = (short)f2b(a.x); p[1] = (short)f2b(a.y);
    p[2] = (short)f2b(a.z); p[3] = (short)f2b(a.w);
    p[4] = (short)f2b(b.x); p[5] = (short)f2b(b.y);
    p[6] = (short)f2b(b.z); p[7] = (short)f2b(b.w);
    return p;
}

__device__ __forceinline__ bf16x8 packbf_s(float4 a, float4 b, float s) {
    bf16x8 p;
    p[0] = (short)f2b(a.x * s); p[1] = (short)f2b(a.y * s);
    p[2] = (short)f2b(a.z * s); p[3] = (short)f2b(a.w * s);
    p[4] = (short)f2b(b.x * s); p[5] = (short)f2b(b.y * s);
    p[6] = (short)f2b(b.z * s); p[7] = (short)f2b(b.w * s);
    return p;
}

// edge_index may arrive as int32 or int64 depending on harness conversion.
__device__ __forceinline__ int ld_idx(const void* ei, long long pos, int is64) {
    if (is64) return (int)((const long long*)ei)[pos];
    return ((const int*)ei)[pos];
}

__global__ void detect64_kernel(const void* ei, int* flag) {
    if (threadIdx.x == 0 && blockIdx.x == 0) {
        const int* p = (const int*)ei;
        int is64 = 1;
        for (int i = 0; i < 64; ++i) {
            if (p[2 * i + 1] != 0) { is64 = 0; break; }
        }
        *flag = is64;
    }
}

// Wc1[320][128]->WT1[128][320]; Wc2[128][64]->WT2[64][128]; W2[320][128]->WU2[128][320]
__global__ void prep_w_kernel(const float* __restrict__ Wc1,
                              const float* __restrict__ Wc2,
                              const float* __restrict__ W2,
                              unsigned short* __restrict__ WT1,
                              unsigned short* __restrict__ WT2,
                              unsigned short* __restrict__ WU2) {
    int i = blockIdx.x * 256 + threadIdx.x;
    if (i < 320 * 128) {
        int k = i >> 7, n = i & 127;
        WT1[n * 320 + k] = f2b(Wc1[i]);
        WU2[n * 320 + k] = f2b(W2[i]);
    }
    if (i < 128 * 64)  { int k = i >> 6, n = i & 63;  WT2[n * 128 + k] = f2b(Wc2[i]); }
}

__global__ void hist_kernel(const void* ei, int E, int* cnt, const int* flag) {
    int is64 = *flag;
    for (int e = blockIdx.x * blockDim.x + threadIdx.x; e < E;
         e += gridDim.x * blockDim.x) {
        int d = ld_idx(ei, (long long)E + e, is64);
        atomicAdd(&cnt[d], 1);
    }
}

// ---- multi-block scan: A = per-block totals, B = scan totals, C = apply ----
__global__ void scanA_kernel(const int* __restrict__ cnt, int* bsum, int n) {
    __shared__ int ps[1024];
    int b = blockIdx.x, t = threadIdx.x;
    int i0 = b * 4096 + t * 4;
    int s = 0;
#pragma unroll
    for (int j = 0; j < 4; ++j) s += (i0 + j < n) ? cnt[i0 + j] : 0;
    ps[t] = s;
    __syncthreads();
    for (int off = 1; off < 1024; off <<= 1) {
        int v = (t >= off) ? ps[t - off] : 0;
        __syncthreads();
        ps[t] += v;
        __syncthreads();
    }
    if (t == 1023) bsum[b] = ps[1023];
}

__global__ void scanB_kernel(int* bsum, int nb, int* row, int n) {
    if (threadIdx.x == 0 && blockIdx.x == 0) {
        int run = 0;
        for (int i = 0; i < nb; ++i) { int v = bsum[i]; bsum[i] = run; run += v; }
        row[n] = run;
    }
}

__global__ void scanC_kernel(const int* __restrict__ cnt,
                             const int* __restrict__ bsum, int* row, int n) {
    __shared__ int ps[1024];
    int b = blockIdx.x, t = threadIdx.x;
    int i0 = b * 4096 + t * 4;
    int v[4];
    int s = 0;
#pragma unroll
    for (int j = 0; j < 4; ++j) { v[j] = (i0 + j < n) ? cnt[i0 + j] : 0; s += v[j]; }
    ps[t] = s;
    __syncthreads();
    for (int off = 1; off < 1024; off <<= 1) {
        int x = (t >= off) ? ps[t - off] : 0;
        __syncthreads();
        ps[t] += x;
        __syncthreads();
    }
    int excl = ps[t] - s + bsum[b];
#pragma unroll
    for (int j = 0; j < 4; ++j) {
        if (i0 + j < n) { row[i0 + j] = excl; excl += v[j]; }
    }
}

// CSR fill storing (edge, src) pairs.
__global__ void fill_kernel(const void* ei, int E, const int* row, int* cursor,
                            int2* epairs, const int* flag) {
    int is64 = *flag;
    for (int e = blockIdx.x * blockDim.x + threadIdx.x; e < E;
         e += gridDim.x * blockDim.x) {
        int d = ld_idx(ei, (long long)E + e, is64);
        int s = ld_idx(ei, e, is64);
        int pos = atomicAdd(&cursor[d], 1);
        epairs[row[d] + pos] = make_int2(e, s);
    }
}

// agg1[node] = [sum x[src] (16) | sum ea (64)]; one wave/node, unroll-4.
__global__ void agg1_kernel(const int2* __restrict__ ep,
                            const float* __restrict__ x,
                            const float* __restrict__ ea,
                            const int* __restrict__ row,
                            float* __restrict__ agg1, int N) {
    int node = blockIdx.x * 4 + (threadIdx.x >> 6);
    int lane = threadIdx.x & 63;
    if (node >= N) return;
    int r0 = row[node], r1 = row[node + 1];
    float s0 = 0.f, s1 = 0.f, s2 = 0.f, s3 = 0.f, xs = 0.f;
    int i = r0;
    for (; i + 4 <= r1; i += 4) {
        int2 p0 = ep[i], p1 = ep[i + 1], p2 = ep[i + 2], p3 = ep[i + 3];
        float e0 = ea[(size_t)p0.x * 64 + lane];
        float e1 = ea[(size_t)p1.x * 64 + lane];
        float e2 = ea[(size_t)p2.x * 64 + lane];
        float e3 = ea[(size_t)p3.x * 64 + lane];
        if (lane < 16)
            xs += x[p0.y * 16 + lane] + x[p1.y * 16 + lane] +
                  x[p2.y * 16 + lane] + x[p3.y * 16 + lane];
        s0 += e0; s1 += e1; s2 += e2; s3 += e3;
    }
    for (; i < r1; ++i) {
        int2 p = ep[i];
        s0 += ea[(size_t)p.x * 64 + lane];
        if (lane < 16) xs += x[p.y * 16 + lane];
    }
    agg1[node * 80 + 16 + lane] = s0 + s1 + s2 + s3;
    if (lane < 16) agg1[node * 80 + lane] = xs;
}

// h1b (bf16) only -- f32 h1 is dead (update2 is MFMA on bf16 inputs).
__global__ void update1_kernel(const float* __restrict__ x,
                               const float* __restrict__ agg1, const int* row,
                               const float* __restrict__ W1,
                               const float* __restrict__ b1,
                               unsigned short* __restrict__ h1b, int N) {
    __shared__ float in_s[8][96];
    int base = blockIdx.x * 8;
    int tid = threadIdx.x;
    for (int idx = tid; idx < 8 * 96; idx += 128) {
        int i = idx / 96, k = idx % 96;
        int node = base + i;
        float v = 0.f;
        if (node < N) {
            if (k < 16) v = x[node * 16 + k];
            else {
                float inv = 1.f / fmaxf((float)(row[node + 1] - row[node]), 1.f);
                v = agg1[node * 80 + (k - 16)] * inv;
            }
        }
        in_s[i][k] = v;
    }
    __syncthreads();
    int j = tid;
    float acc[8];
#pragma unroll
    for (int i = 0; i < 8; ++i) acc[i] = 0.f;
    for (int k = 0; k < 96; ++k) {
        float w = W1[k * 128 + j];
#pragma unroll
        for (int i = 0; i < 8; ++i) acc[i] += in_s[i][k] * w;
    }
    float bj = b1[j];
#pragma unroll
    for (int i = 0; i < 8; ++i) {
        int node = base + i;
        if (node < N) h1b[node * 128 + j] = f2b(fmaxf(acc[i] + bj, 0.f));
    }
}

// agg2[node] = sum h1b[src] (128 cols, bf16 gather, f32 accum). Unroll-4.
__global__ void agg2_kernel(const int2* __restrict__ ep,
                            const unsigned int* __restrict__ h1b32,
                            const int* __restrict__ row,
                            float* __restrict__ agg2, int N) {
    int node = blockIdx.x * 4 + (threadIdx.x >> 6);
    int lane = threadIdx.x & 63;
    if (node >= N) return;
    int r0 = row[node], r1 = row[node + 1];
    float a0 = 0.f, a1 = 0.f, a2 = 0.f, a3 = 0.f;   // col 2*lane
    float b0 = 0.f, b1 = 0.f, b2 = 0.f, b3 = 0.f;   // col 2*lane+1
    int i = r0;
    for (; i + 4 <= r1; i += 4) {
        unsigned int u0 = h1b32[(size_t)ep[i].y     * 64 + lane];
        unsigned int u1 = h1b32[(size_t)ep[i + 1].y * 64 + lane];
        unsigned int u2 = h1b32[(size_t)ep[i + 2].y * 64 + lane];
        unsigned int u3 = h1b32[(size_t)ep[i + 3].y * 64 + lane];
        a0 += __builtin_bit_cast(float, u0 << 16);
        b0 += __builtin_bit_cast(float, u0 & 0xffff0000u);
        a1 += __builtin_bit_cast(float, u1 << 16);
        b1 += __builtin_bit_cast(float, u1 & 0xffff0000u);
        a2 += __builtin_bit_cast(float, u2 << 16);
        b2 += __builtin_bit_cast(float, u2 & 0xffff0000u);
        a3 += __builtin_bit_cast(float, u3 << 16);
        b3 += __builtin_bit_cast(float, u3 & 0xffff0000u);
    }
    for (; i < r1; ++i) {
        unsigned int u = h1b32[(size_t)ep[i].y * 64 + lane];
        a0 += __builtin_bit_cast(float, u << 16);
        b0 += __builtin_bit_cast(float, u & 0xffff0000u);
    }
    agg2[node * 128 + 2 * lane]     = a0 + a1 + a2 + a3;
    agg2[node * 128 + 2 * lane + 1] = b0 + b1 + b2 + b3;
}

// ---------------------------------------------------------------------------
// update2 as MFMA (classifier phase-A structure): 512 thr, 8 waves, 256-node
// tiles, 32 nodes/wave. in = [h1b | agg2/deg | agg1_ea/deg] bf16, K=320,
// W2^T frags LDS-resident (80 KB). h2b written directly from accumulators.
// ---------------------------------------------------------------------------
__global__ __launch_bounds__(512, 2) void update2_mfma(
    const unsigned short* __restrict__ h1b, const float* __restrict__ agg2,
    const float* __restrict__ agg1, const int* __restrict__ row,
    const unsigned short* __restrict__ WU2, const float* __restrict__ b2,
    unsigned short* __restrict__ h2b, int N) {
    __shared__ __align__(16) unsigned short wu[40960];  // 40 frags x 128 j x 8

    const int tid = threadIdx.x;
    const int l  = tid & 63;
    const int w  = tid >> 6;
    const int lm = l & 15;
    const int g  = l >> 4;

    for (int i = tid; i < 5120; i += 512) {
        int f = i >> 7, j = i & 127;
        uint4 v = *(const uint4*)(WU2 + (size_t)j * 320 + (f >> 2) * 32 + (f & 3) * 8);
        *(uint4*)(wu + (size_t)i * 8) = v;
    }
    const f32x4 zero = {0.f, 0.f, 0.f, 0.f};
    __syncthreads();

    const int tbase = blockIdx.x * 256;

    bf16x8 A[2][10];
#pragma unroll
    for (int h = 0; h < 2; ++h) {
        const int node = tbase + 32 * w + 16 * h + lm;
        const int nc = min(node, N - 1);
        const unsigned short* rh = h1b + (size_t)nc * 128 + g * 8;
#pragma unroll
        for (int kt = 0; kt < 4; ++kt) A[h][kt] = *(const bf16x8*)(rh + kt * 32);
        float invd = 1.f / fmaxf((float)(row[nc + 1] - row[nc]), 1.f);
        const float* pa2 = agg2 + (size_t)nc * 128 + g * 8;
#pragma unroll
        for (int kt = 0; kt < 4; ++kt) {
            float4 f0 = *(const float4*)(pa2 + kt * 32);
            float4 f1 = *(const float4*)(pa2 + kt * 32 + 4);
            A[h][4 + kt] = packbf_s(f0, f1, invd);
        }
        const float* pa1 = agg1 + (size_t)nc * 80 + 16 + g * 8;
#pragma unroll
        for (int t = 0; t < 2; ++t) {
            float4 f0 = *(const float4*)(pa1 + t * 32);
            float4 f1 = *(const float4*)(pa1 + t * 32 + 4);
            A[h][8 + t] = packbf_s(f0, f1, invd);
        }
    }

    f32x4 acc[2][8];
#pragma unroll
    for (int h = 0; h < 2; ++h)
#pragma unroll
        for (int n = 0; n < 8; ++n) acc[h][n] = zero;
#pragma unroll
    for (int kt = 0; kt < 10; ++kt) {
        const unsigned short* wb = wu + ((size_t)(kt * 4 + g) * 128) * 8;
#pragma unroll
        for (int n = 0; n < 8; ++n) {
            bf16x8 b = *(const bf16x8*)(wb + (size_t)(16 * n + lm) * 8);
            acc[0][n] = __builtin_amdgcn_mfma_f32_16x16x32_bf16(A[0][kt], b, acc[0][n], 0, 0, 0);
            acc[1][n] = __builtin_amdgcn_mfma_f32_16x16x32_bf16(A[1][kt], b, acc[1][n], 0, 0, 0);
        }
    }
#pragma unroll
    for (int n = 0; n < 8; ++n) {
        float bj = b2[16 * n + lm];
#pragma unroll
        for (int h = 0; h < 2; ++h)
#pragma unroll
            for (int r = 0; r < 4; ++r) {
                int node = tbase + 32 * w + 16 * h + 4 * g + r;
                if (node < N)
                    h2b[(size_t)node * 128 + 16 * n + lm] =
                        f2b(fmaxf(acc[h][n][r] + bj, 0.f));
            }
    }
}

// ---------------------------------------------------------------------------
// Persistent MFMA edge classifier (R16, edge order). 512 threads (8 waves),
// 256-edge tiles, 32 edges per wave; Wc1 frags LDS-resident; WT2 from L1;
// z1 via LDS [256][134]; phase C in registers + shfl.
// LDS = 81920 + 68608 = 150528 B.
// ---------------------------------------------------------------------------
__global__ __launch_bounds__(512, 2) void classifier_mfma(
    const void* ei, const unsigned short* __restrict__ h2b,
    const float* __restrict__ ea,
    const unsigned short* __restrict__ WT1, const float* __restrict__ bc1,
    const unsigned short* __restrict__ WT2, const float* __restrict__ bc2,
    const float* __restrict__ Wc3, const float* __restrict__ bc3,
    float* __restrict__ out, int E, const int* flag) {
    __shared__ __align__(16) char smem[150528];
    unsigned short* wt1f = (unsigned short*)smem;             // 40 frags x 128 j
    unsigned short* z1b  = (unsigned short*)(smem + 81920);   // [256][134]

    const int tid = threadIdx.x;
    const int is64 = *flag;
    const int l  = tid & 63;
    const int w  = tid >> 6;    // wave 0..7
    const int lm = l & 15;
    const int g  = l >> 4;

    for (int i = tid; i < 5120; i += 512) {
        int f = i >> 7, j = i & 127;
        uint4 v = *(const uint4*)(WT1 + (size_t)j * 320 + (f >> 2) * 32 + (f & 3) * 8);
        *(uint4*)(wt1f + (size_t)i * 8) = v;
    }
    float wc3r[4];
#pragma unroll
    for (int n = 0; n < 4; ++n) wc3r[n] = Wc3[16 * n + lm];
    const float bc3s = bc3[0];
    const f32x4 zero = {0.f, 0.f, 0.f, 0.f};
    __syncthreads();   // ONLY barrier

    const int T = (E + 255) / 256;
    for (int tile = blockIdx.x; tile < T; tile += gridDim.x) {
        const int tbase = tile * 256;

        bf16x8 A[2][10];
#pragma unroll
        for (int h = 0; h < 2; ++h) {
            const int e  = tbase + 32 * w + 16 * h + lm;
            const int ec = min(e, E - 1);
            const int sE = ld_idx(ei, ec, is64);
            const int dE = ld_idx(ei, (long long)E + ec, is64);
            const unsigned short* rs = h2b + (size_t)sE * 128 + g * 8;
            const unsigned short* rd = h2b + (size_t)dE * 128 + g * 8;
#pragma unroll
            for (int kt = 0; kt < 4; ++kt) A[h][kt] = *(const bf16x8*)(rs + kt * 32);
#pragma unroll
            for (int kt = 0; kt < 4; ++kt) A[h][4 + kt] = *(const bf16x8*)(rd + kt * 32);
            const float* pe = ea + (size_t)ec * 64 + g * 8;
            float4 f0 = *(const float4*)pe,        f1 = *(const float4*)(pe + 4);
            float4 f2 = *(const float4*)(pe + 32), f3 = *(const float4*)(pe + 36);
            A[h][8] = packbf(f0, f1);
            A[h][9] = packbf(f2, f3);
        }

        f32x4 acc[2][8];
#pragma unroll
        for (int h = 0; h < 2; ++h)
#pragma unroll
            for (int n = 0; n < 8; ++n) acc[h][n] = zero;
#pragma unroll
        for (int kt = 0; kt < 10; ++kt) {
            const unsigned short* wb = wt1f + ((size_t)(kt * 4 + g) * 128) * 8;
#pragma unroll
            for (int n = 0; n < 8; ++n) {
                bf16x8 b = *(const bf16x8*)(wb + (size_t)(16 * n + lm) * 8);
                acc[0][n] = __builtin_amdgcn_mfma_f32_16x16x32_bf16(A[0][kt], b, acc[0][n], 0, 0, 0);
                acc[1][n] = __builtin_amdgcn_mfma_f32_16x16x32_bf16(A[1][kt], b, acc[1][n], 0, 0, 0);
            }
        }
#pragma unroll
        for (int n = 0; n < 8; ++n) {
            float bj = bc1[16 * n + lm];
#pragma unroll
            for (int h = 0; h < 2; ++h)
#pragma unroll
                for (int r = 0; r < 4; ++r) {
                    float v = fmaxf(acc[h][n][r] + bj, 0.f);
                    z1b[(size_t)(32 * w + 16 * h + g * 4 + r) * 134 + 16 * n + lm] = f2b(v);
                }
        }

        f32x4 acc2[2][4];
#pragma unroll
        for (int h = 0; h < 2; ++h)
#pragma unroll
            for (int n = 0; n < 4; ++n) acc2[h][n] = zero;
        const unsigned short* brow0 = z1b + (size_t)(32 * w + lm) * 134;
        const unsigned short* brow1 = z1b + (size_t)(32 * w + 16 + lm) * 134;
#pragma unroll
        for (int kt = 0; kt < 4; ++kt) {
            bf16x8 a0 = *(const bf16x8*)(brow0 + kt * 32 + g * 8);
            bf16x8 a1 = *(const bf16x8*)(brow1 + kt * 32 + g * 8);
#pragma unroll
            for (int n = 0; n < 4; ++n) {
                bf16x8 b = *(const bf16x8*)(WT2 + (size_t)(16 * n + lm) * 128 + kt * 32 + g * 8);
                acc2[0][n] = __builtin_amdgcn_mfma_f32_16x16x32_bf16(a0, b, acc2[0][n], 0, 0, 0);
                acc2[1][n] = __builtin_amdgcn_mfma_f32_16x16x32_bf16(a1, b, acc2[1][n], 0, 0, 0);
            }
        }

#pragma unroll
        for (int h = 0; h < 2; ++h) {
            float p[4];
#pragma unroll
            for (int r = 0; r < 4; ++r) p[r] = 0.f;
#pragma unroll
            for (int n = 0; n < 4; ++n) {
                float bj = bc2[16 * n + lm];
#pragma unroll
                for (int r = 0; r < 4; ++r) {
                    float z = fmaxf(acc2[h][n][r] + bj, 0.f);
                    p[r] += z * wc3r[n];
                }
            }
#pragma unroll
            for (int r = 0; r < 4; ++r) {
                p[r] += __shfl_xor(p[r], 1, 16);
                p[r] += __shfl_xor(p[r], 2, 16);
                p[r] += __shfl_xor(p[r], 4, 16);
                p[r] += __shfl_xor(p[r], 8, 16);
            }
            if (lm == 0) {
#pragma unroll
                for (int r = 0; r < 4; ++r) {
                    int eo = tbase + 32 * w + 16 * h + 4 * g + r;
                    if (eo < E) out[eo] = p[r] + bc3s;
                }
            }
        }
    }
}

extern "C" void kernel_launch(void* const* d_in, const int* in_sizes, int n_in,
                              void* d_out, int out_size, void* d_ws,
                              size_t ws_size, hipStream_t stream) {
    const float* x   = (const float*)d_in[0];
    const void*  ei  = d_in[1];
    const float* ea  = (const float*)d_in[2];
    const float* W1  = (const float*)d_in[3];
    const float* b1  = (const float*)d_in[4];
    const float* W2  = (const float*)d_in[5];
    const float* b2  = (const float*)d_in[6];
    const float* Wc1 = (const float*)d_in[7];
    const float* bc1 = (const float*)d_in[8];
    const float* Wc2 = (const float*)d_in[9];
    const float* bc2 = (const float*)d_in[10];
    const float* Wc3 = (const float*)d_in[11];
    const float* bc3 = (const float*)d_in[12];
    float* out = (float*)d_out;

    int N = in_sizes[0] / 16;   // 50000
    int E = in_sizes[2] / 64;   // 800000

    char* ws = (char*)d_ws;
    size_t off = 0;
    auto alloc = [&](size_t bytes) {
        void* p = ws + off;
        off += (bytes + 511) & ~(size_t)511;
        return p;
    };
    int*            cnt    = (int*)alloc((size_t)N * 4);
    int*            cursor = (int*)alloc((size_t)N * 4);
    int*            row    = (int*)alloc((size_t)(N + 1) * 4);
    int*            bsum   = (int*)alloc(64 * 4);
    int2*           epairs = (int2*)alloc((size_t)E * 8);
    int*            flag   = (int*)alloc(4);
    float*          agg1   = (float*)alloc((size_t)N * 80 * 4);
    unsigned short* h1b    = (unsigned short*)alloc((size_t)N * 128 * 2);
    float*          agg2   = (float*)alloc((size_t)N * 128 * 4);
    unsigned short* h2b    = (unsigned short*)alloc((size_t)N * 128 * 2);
    unsigned short* WT1    = (unsigned short*)alloc((size_t)128 * 320 * 2);
    unsigned short* WT2    = (unsigned short*)alloc((size_t)64 * 128 * 2);
    unsigned short* WU2    = (unsigned short*)alloc((size_t)128 * 320 * 2);
    (void)ws_size; (void)n_in; (void)out_size;

    int nb = (N + 4095) / 4096;   // 13

    hipMemsetAsync(cnt, 0, (size_t)N * 4, stream);
    hipMemsetAsync(cursor, 0, (size_t)N * 4, stream);

    detect64_kernel<<<1, 64, 0, stream>>>(ei, flag);
    prep_w_kernel<<<160, 256, 0, stream>>>(Wc1, Wc2, W2, WT1, WT2, WU2);
    hist_kernel<<<1024, 256, 0, stream>>>(ei, E, cnt, flag);
    scanA_kernel<<<nb, 1024, 0, stream>>>(cnt, bsum, N);
    scanB_kernel<<<1, 64, 0, stream>>>(bsum, nb, row, N);
    scanC_kernel<<<nb, 1024, 0, stream>>>(cnt, bsum, row, N);
    fill_kernel<<<1024, 256, 0, stream>>>(ei, E, row, cursor, epairs, flag);
    agg1_kernel<<<(N + 3) / 4, 256, 0, stream>>>(epairs, x, ea, row, agg1, N);
    update1_kernel<<<(N + 7) / 8, 128, 0, stream>>>(x, agg1, row, W1, b1, h1b, N);
    agg2_kernel<<<(N + 3) / 4, 256, 0, stream>>>(epairs, (const unsigned int*)h1b, row, agg2, N);
    update2_mfma<<<(N + 255) / 256, 512, 0, stream>>>(h1b, agg2, agg1, row, WU2, b2, h2b, N);
    classifier_mfma<<<256, 512, 0, stream>>>(ei, h2b, ea, WT1, bc1,
                                             WT2, bc2, Wc3, bc3,
                                             out, E, flag);
}

// Round 19
// 380.994 us; speedup vs baseline: 1.6603x; 1.0646x over previous
//
#include <hip/hip_runtime.h>

// ---------------------------------------------------------------------------
// E-GraphSAGE forward. Stages:
//   1. CSR build by dst (histogram + multi-block scan + fill -> (edge,src))
//   2. agg1 [N,80]  = sums of [x[src](16) | ea(64)] per dst  (unroll-8)
//   3. h1b [N,128]  = ReLU([x | agg1/deg] @ W1 + b1), bf16 MFMA (K=96)
//   4. agg2 [N,128] = sums of h1b[src] per dst (bf16 gather, unroll-8)
//   5. h2b [N,128]  = ReLU([h1b | agg2/deg | agg1_ea/deg] @ W2 + b2), MFMA
//   6. out [E,1]    = edge MLP 320->128->64->1, bf16 MFMA (R16 structure;
//                     ~150us = L3 random-gather floor for 2x256B rows/edge)
// ---------------------------------------------------------------------------

typedef __attribute__((ext_vector_type(8))) short bf16x8;
typedef __attribute__((ext_vector_type(4))) float f32x4;

__device__ __forceinline__ unsigned short f2b(float f) {   // f32 -> bf16 RNE
    unsigned int u = __builtin_bit_cast(unsigned int, f);
    u += 0x7fffu + ((u >> 16) & 1u);
    return (unsigned short)(u >> 16);
}

__device__ __forceinline__ bf16x8 packbf(float4 a, float4 b) {
    bf16x8 p;
    p[0] = (short)f2b(a.x); p[1] = (short)f2b(a.y);
    p[2] = (short)f2b(a.z); p[3] = (short)f2b(a.w);
    p[4] = (short)f2b(b.x); p[5] = (short)f2b(b.y);
    p[6] = (short)f2b(b.z); p[7] = (short)f2b(b.w);
    return p;
}

__device__ __forceinline__ bf16x8 packbf_s(float4 a, float4 b, float s) {
    bf16x8 p;
    p[0] = (short)f2b(a.x * s); p[1] = (short)f2b(a.y * s);
    p[2] = (short)f2b(a.z * s); p[3] = (short)f2b(a.w * s);
    p[4] = (short)f2b(b.x * s); p[5] = (short)f2b(b.y * s);
    p[6] = (short)f2b(b.z * s); p[7] = (short)f2b(b.w * s);
    return p;
}

// edge_index may arrive as int32 or int64 depending on harness conversion.
__device__ __forceinline__ int ld_idx(const void* ei, long long pos, int is64) {
    if (is64) return (int)((const long long*)ei)[pos];
    return ((const int*)ei)[pos];
}

__global__ void detect64_kernel(const void* ei, int* flag) {
    if (threadIdx.x == 0 && blockIdx.x == 0) {
        const int* p = (const int*)ei;
        int is64 = 1;
        for (int i = 0; i < 64; ++i) {
            if (p[2 * i + 1] != 0) { is64 = 0; break; }
        }
        *flag = is64;
    }
}

// Wc1[320][128]->WT1[128][320]; Wc2[128][64]->WT2[64][128];
// W2[320][128]->WU2[128][320]; W1[96][128]->WU1[128][96]  (all bf16)
__global__ void prep_w_kernel(const float* __restrict__ Wc1,
                              const float* __restrict__ Wc2,
                              const float* __restrict__ W2,
                              const float* __restrict__ W1,
                              unsigned short* __restrict__ WT1,
                              unsigned short* __restrict__ WT2,
                              unsigned short* __restrict__ WU2,
                              unsigned short* __restrict__ WU1) {
    int i = blockIdx.x * 256 + threadIdx.x;
    if (i < 320 * 128) {
        int k = i >> 7, n = i & 127;
        WT1[n * 320 + k] = f2b(Wc1[i]);
        WU2[n * 320 + k] = f2b(W2[i]);
    }
    if (i < 128 * 64)  { int k = i >> 6, n = i & 63;  WT2[n * 128 + k] = f2b(Wc2[i]); }
    if (i < 96 * 128)  { int k = i >> 7, n = i & 127; WU1[n * 96 + k] = f2b(W1[i]); }
}

__global__ void hist_kernel(const void* ei, int E, int* cnt, const int* flag) {
    int is64 = *flag;
    for (int e = blockIdx.x * blockDim.x + threadIdx.x; e < E;
         e += gridDim.x * blockDim.x) {
        int d = ld_idx(ei, (long long)E + e, is64);
        atomicAdd(&cnt[d], 1);
    }
}

// ---- multi-block scan: A = per-block totals, B = scan totals, C = apply ----
__global__ void scanA_kernel(const int* __restrict__ cnt, int* bsum, int n) {
    __shared__ int ps[1024];
    int b = blockIdx.x, t = threadIdx.x;
    int i0 = b * 4096 + t * 4;
    int s = 0;
#pragma unroll
    for (int j = 0; j < 4; ++j) s += (i0 + j < n) ? cnt[i0 + j] : 0;
    ps[t] = s;
    __syncthreads();
    for (int off = 1; off < 1024; off <<= 1) {
        int v = (t >= off) ? ps[t - off] : 0;
        __syncthreads();
        ps[t] += v;
        __syncthreads();
    }
    if (t == 1023) bsum[b] = ps[1023];
}

__global__ void scanB_kernel(int* bsum, int nb, int* row, int n) {
    if (threadIdx.x == 0 && blockIdx.x == 0) {
        int run = 0;
        for (int i = 0; i < nb; ++i) { int v = bsum[i]; bsum[i] = run; run += v; }
        row[n] = run;
    }
}

__global__ void scanC_kernel(const int* __restrict__ cnt,
                             const int* __restrict__ bsum, int* row, int n) {
    __shared__ int ps[1024];
    int b = blockIdx.x, t = threadIdx.x;
    int i0 = b * 4096 + t * 4;
    int v[4];
    int s = 0;
#pragma unroll
    for (int j = 0; j < 4; ++j) { v[j] = (i0 + j < n) ? cnt[i0 + j] : 0; s += v[j]; }
    ps[t] = s;
    __syncthreads();
    for (int off = 1; off < 1024; off <<= 1) {
        int x = (t >= off) ? ps[t - off] : 0;
        __syncthreads();
        ps[t] += x;
        __syncthreads();
    }
    int excl = ps[t] - s + bsum[b];
#pragma unroll
    for (int j = 0; j < 4; ++j) {
        if (i0 + j < n) { row[i0 + j] = excl; excl += v[j]; }
    }
}

// CSR fill storing (edge, src) pairs.
__global__ void fill_kernel(const void* ei, int E, const int* row, int* cursor,
                            int2* epairs, const int* flag) {
    int is64 = *flag;
    for (int e = blockIdx.x * blockDim.x + threadIdx.x; e < E;
         e += gridDim.x * blockDim.x) {
        int d = ld_idx(ei, (long long)E + e, is64);
        int s = ld_idx(ei, e, is64);
        int pos = atomicAdd(&cursor[d], 1);
        epairs[row[d] + pos] = make_int2(e, s);
    }
}

// agg1[node] = [sum x[src] (16) | sum ea (64)]; one wave/node, unroll-8.
__global__ void agg1_kernel(const int2* __restrict__ ep,
                            const float* __restrict__ x,
                            const float* __restrict__ ea,
                            const int* __restrict__ row,
                            float* __restrict__ agg1, int N) {
    int node = blockIdx.x * 4 + (threadIdx.x >> 6);
    int lane = threadIdx.x & 63;
    if (node >= N) return;
    int r0 = row[node], r1 = row[node + 1];
    float s0 = 0.f, s1 = 0.f, s2 = 0.f, s3 = 0.f;
    float s4 = 0.f, s5 = 0.f, s6 = 0.f, s7 = 0.f, xs = 0.f;
    int i = r0;
    for (; i + 8 <= r1; i += 8) {
        int2 p0 = ep[i],     p1 = ep[i + 1], p2 = ep[i + 2], p3 = ep[i + 3];
        int2 p4 = ep[i + 4], p5 = ep[i + 5], p6 = ep[i + 6], p7 = ep[i + 7];
        float e0 = ea[(size_t)p0.x * 64 + lane];
        float e1 = ea[(size_t)p1.x * 64 + lane];
        float e2 = ea[(size_t)p2.x * 64 + lane];
        float e3 = ea[(size_t)p3.x * 64 + lane];
        float e4 = ea[(size_t)p4.x * 64 + lane];
        float e5 = ea[(size_t)p5.x * 64 + lane];
        float e6 = ea[(size_t)p6.x * 64 + lane];
        float e7 = ea[(size_t)p7.x * 64 + lane];
        if (lane < 16)
            xs += x[p0.y * 16 + lane] + x[p1.y * 16 + lane] +
                  x[p2.y * 16 + lane] + x[p3.y * 16 + lane] +
                  x[p4.y * 16 + lane] + x[p5.y * 16 + lane] +
                  x[p6.y * 16 + lane] + x[p7.y * 16 + lane];
        s0 += e0; s1 += e1; s2 += e2; s3 += e3;
        s4 += e4; s5 += e5; s6 += e6; s7 += e7;
    }
    for (; i < r1; ++i) {
        int2 p = ep[i];
        s0 += ea[(size_t)p.x * 64 + lane];
        if (lane < 16) xs += x[p.y * 16 + lane];
    }
    agg1[node * 80 + 16 + lane] = ((s0 + s1) + (s2 + s3)) + ((s4 + s5) + (s6 + s7));
    if (lane < 16) agg1[node * 80 + lane] = xs;
}

// ---------------------------------------------------------------------------
// update1 as MFMA: h1b = ReLU([x | agg1/deg] @ W1 + b1), K=96 (3 k-frags).
// 512 thr, 8 waves, 256-node tiles, 32 nodes/wave. W1^T frags in LDS (24 KB).
// ---------------------------------------------------------------------------
__global__ __launch_bounds__(512, 2) void update1_mfma(
    const float* __restrict__ x, const float* __restrict__ agg1,
    const int* __restrict__ row, const unsigned short* __restrict__ WU1,
    const float* __restrict__ b1, unsigned short* __restrict__ h1b, int N) {
    __shared__ __align__(16) unsigned short wu[12288];  // 12 frags x 128 j x 8

    const int tid = threadIdx.x;
    const int l  = tid & 63;
    const int w  = tid >> 6;
    const int lm = l & 15;
    const int g  = l >> 4;

    for (int i = tid; i < 1536; i += 512) {
        int f = i >> 7, j = i & 127;
        uint4 v = *(const uint4*)(WU1 + (size_t)j * 96 + (f >> 2) * 32 + (f & 3) * 8);
        *(uint4*)(wu + (size_t)i * 8) = v;
    }
    const f32x4 zero = {0.f, 0.f, 0.f, 0.f};
    __syncthreads();

    const int tbase = blockIdx.x * 256;

    bf16x8 A[2][3];
#pragma unroll
    for (int h = 0; h < 2; ++h) {
        const int node = tbase + 32 * w + 16 * h + lm;
        const int nc = min(node, N - 1);
        float invd = 1.f / fmaxf((float)(row[nc + 1] - row[nc]), 1.f);
        // kt=0: k 0..31 = [x(16) | agg1[0..16)*inv]
        if (g < 2) {
            const float* px = x + (size_t)nc * 16 + g * 8;
            A[h][0] = packbf(*(const float4*)px, *(const float4*)(px + 4));
        } else {
            const float* pa = agg1 + (size_t)nc * 80 + (g - 2) * 8;
            A[h][0] = packbf_s(*(const float4*)pa, *(const float4*)(pa + 4), invd);
        }
        // kt=1: k 32..63 = agg1[16..48)*inv
        {
            const float* pa = agg1 + (size_t)nc * 80 + 16 + g * 8;
            A[h][1] = packbf_s(*(const float4*)pa, *(const float4*)(pa + 4), invd);
        }
        // kt=2: k 64..95 = agg1[48..80)*inv
        {
            const float* pa = agg1 + (size_t)nc * 80 + 48 + g * 8;
            A[h][2] = packbf_s(*(const float4*)pa, *(const float4*)(pa + 4), invd);
        }
    }

    f32x4 acc[2][8];
#pragma unroll
    for (int h = 0; h < 2; ++h)
#pragma unroll
        for (int n = 0; n < 8; ++n) acc[h][n] = zero;
#pragma unroll
    for (int kt = 0; kt < 3; ++kt) {
        const unsigned short* wb = wu + ((size_t)(kt * 4 + g) * 128) * 8;
#pragma unroll
        for (int n = 0; n < 8; ++n) {
            bf16x8 b = *(const bf16x8*)(wb + (size_t)(16 * n + lm) * 8);
            acc[0][n] = __builtin_amdgcn_mfma_f32_16x16x32_bf16(A[0][kt], b, acc[0][n], 0, 0, 0);
            acc[1][n] = __builtin_amdgcn_mfma_f32_16x16x32_bf16(A[1][kt], b, acc[1][n], 0, 0, 0);
        }
    }
#pragma unroll
    for (int n = 0; n < 8; ++n) {
        float bj = b1[16 * n + lm];
#pragma unroll
        for (int h = 0; h < 2; ++h)
#pragma unroll
            for (int r = 0; r < 4; ++r) {
                int node = tbase + 32 * w + 16 * h + 4 * g + r;
                if (node < N)
                    h1b[(size_t)node * 128 + 16 * n + lm] =
                        f2b(fmaxf(acc[h][n][r] + bj, 0.f));
            }
    }
}

// agg2[node] = sum h1b[src] (128 cols, bf16 gather, f32 accum). Unroll-8.
__global__ void agg2_kernel(const int2* __restrict__ ep,
                            const unsigned int* __restrict__ h1b32,
                            const int* __restrict__ row,
                            float* __restrict__ agg2, int N) {
    int node = blockIdx.x * 4 + (threadIdx.x >> 6);
    int lane = threadIdx.x & 63;
    if (node >= N) return;
    int r0 = row[node], r1 = row[node + 1];
    float a0 = 0.f, a1 = 0.f, a2 = 0.f, a3 = 0.f;
    float a4 = 0.f, a5 = 0.f, a6 = 0.f, a7 = 0.f;
    float b0 = 0.f, b1 = 0.f, b2 = 0.f, b3 = 0.f;
    float b4 = 0.f, b5 = 0.f, b6 = 0.f, b7 = 0.f;
    int i = r0;
    for (; i + 8 <= r1; i += 8) {
        unsigned int u0 = h1b32[(size_t)ep[i].y     * 64 + lane];
        unsigned int u1 = h1b32[(size_t)ep[i + 1].y * 64 + lane];
        unsigned int u2 = h1b32[(size_t)ep[i + 2].y * 64 + lane];
        unsigned int u3 = h1b32[(size_t)ep[i + 3].y * 64 + lane];
        unsigned int u4 = h1b32[(size_t)ep[i + 4].y * 64 + lane];
        unsigned int u5 = h1b32[(size_t)ep[i + 5].y * 64 + lane];
        unsigned int u6 = h1b32[(size_t)ep[i + 6].y * 64 + lane];
        unsigned int u7 = h1b32[(size_t)ep[i + 7].y * 64 + lane];
        a0 += __builtin_bit_cast(float, u0 << 16);
        b0 += __builtin_bit_cast(float, u0 & 0xffff0000u);
        a1 += __builtin_bit_cast(float, u1 << 16);
        b1 += __builtin_bit_cast(float, u1 & 0xffff0000u);
        a2 += __builtin_bit_cast(float, u2 << 16);
        b2 += __builtin_bit_cast(float, u2 & 0xffff0000u);
        a3 += __builtin_bit_cast(float, u3 << 16);
        b3 += __builtin_bit_cast(float, u3 & 0xffff0000u);
        a4 += __builtin_bit_cast(float, u4 << 16);
        b4 += __builtin_bit_cast(float, u4 & 0xffff0000u);
        a5 += __builtin_bit_cast(float, u5 << 16);
        b5 += __builtin_bit_cast(float, u5 & 0xffff0000u);
        a6 += __builtin_bit_cast(float, u6 << 16);
        b6 += __builtin_bit_cast(float, u6 & 0xffff0000u);
        a7 += __builtin_bit_cast(float, u7 << 16);
        b7 += __builtin_bit_cast(float, u7 & 0xffff0000u);
    }
    for (; i < r1; ++i) {
        unsigned int u = h1b32[(size_t)ep[i].y * 64 + lane];
        a0 += __builtin_bit_cast(float, u << 16);
        b0 += __builtin_bit_cast(float, u & 0xffff0000u);
    }
    agg2[node * 128 + 2 * lane]     = ((a0 + a1) + (a2 + a3)) + ((a4 + a5) + (a6 + a7));
    agg2[node * 128 + 2 * lane + 1] = ((b0 + b1) + (b2 + b3)) + ((b4 + b5) + (b6 + b7));
}

// ---------------------------------------------------------------------------
// update2 as MFMA (validated R18): 512 thr, 256-node tiles, K=320,
// in = [h1b | agg2/deg | agg1_ea/deg] bf16, W2^T frags LDS (80 KB).
// ---------------------------------------------------------------------------
__global__ __launch_bounds__(512, 2) void update2_mfma(
    const unsigned short* __restrict__ h1b, const float* __restrict__ agg2,
    const float* __restrict__ agg1, const int* __restrict__ row,
    const unsigned short* __restrict__ WU2, const float* __restrict__ b2,
    unsigned short* __restrict__ h2b, int N) {
    __shared__ __align__(16) unsigned short wu[40960];  // 40 frags x 128 j x 8

    const int tid = threadIdx.x;
    const int l  = tid & 63;
    const int w  = tid >> 6;
    const int lm = l & 15;
    const int g  = l >> 4;

    for (int i = tid; i < 5120; i += 512) {
        int f = i >> 7, j = i & 127;
        uint4 v = *(const uint4*)(WU2 + (size_t)j * 320 + (f >> 2) * 32 + (f & 3) * 8);
        *(uint4*)(wu + (size_t)i * 8) = v;
    }
    const f32x4 zero = {0.f, 0.f, 0.f, 0.f};
    __syncthreads();

    const int tbase = blockIdx.x * 256;

    bf16x8 A[2][10];
#pragma unroll
    for (int h = 0; h < 2; ++h) {
        const int node = tbase + 32 * w + 16 * h + lm;
        const int nc = min(node, N - 1);
        const unsigned short* rh = h1b + (size_t)nc * 128 + g * 8;
#pragma unroll
        for (int kt = 0; kt < 4; ++kt) A[h][kt] = *(const bf16x8*)(rh + kt * 32);
        float invd = 1.f / fmaxf((float)(row[nc + 1] - row[nc]), 1.f);
        const float* pa2 = agg2 + (size_t)nc * 128 + g * 8;
#pragma unroll
        for (int kt = 0; kt < 4; ++kt) {
            float4 f0 = *(const float4*)(pa2 + kt * 32);
            float4 f1 = *(const float4*)(pa2 + kt * 32 + 4);
            A[h][4 + kt] = packbf_s(f0, f1, invd);
        }
        const float* pa1 = agg1 + (size_t)nc * 80 + 16 + g * 8;
#pragma unroll
        for (int t = 0; t < 2; ++t) {
            float4 f0 = *(const float4*)(pa1 + t * 32);
            float4 f1 = *(const float4*)(pa1 + t * 32 + 4);
            A[h][8 + t] = packbf_s(f0, f1, invd);
        }
    }

    f32x4 acc[2][8];
#pragma unroll
    for (int h = 0; h < 2; ++h)
#pragma unroll
        for (int n = 0; n < 8; ++n) acc[h][n] = zero;
#pragma unroll
    for (int kt = 0; kt < 10; ++kt) {
        const unsigned short* wb = wu + ((size_t)(kt * 4 + g) * 128) * 8;
#pragma unroll
        for (int n = 0; n < 8; ++n) {
            bf16x8 b = *(const bf16x8*)(wb + (size_t)(16 * n + lm) * 8);
            acc[0][n] = __builtin_amdgcn_mfma_f32_16x16x32_bf16(A[0][kt], b, acc[0][n], 0, 0, 0);
            acc[1][n] = __builtin_amdgcn_mfma_f32_16x16x32_bf16(A[1][kt], b, acc[1][n], 0, 0, 0);
        }
    }
#pragma unroll
    for (int n = 0; n < 8; ++n) {
        float bj = b2[16 * n + lm];
#pragma unroll
        for (int h = 0; h < 2; ++h)
#pragma unroll
            for (int r = 0; r < 4; ++r) {
                int node = tbase + 32 * w + 16 * h + 4 * g + r;
                if (node < N)
                    h2b[(size_t)node * 128 + 16 * n + lm] =
                        f2b(fmaxf(acc[h][n][r] + bj, 0.f));
            }
    }
}

// ---------------------------------------------------------------------------
// Persistent MFMA edge classifier (R16, edge order). 512 threads (8 waves),
// 256-edge tiles, 32 edges per wave; Wc1 frags LDS-resident; WT2 from L1;
// z1 via LDS [256][134]; phase C in registers + shfl.
// LDS = 81920 + 68608 = 150528 B.  ~150us = L3 random-gather floor.
// ---------------------------------------------------------------------------
__global__ __launch_bounds__(512, 2) void classifier_mfma(
    const void* ei, const unsigned short* __restrict__ h2b,
    const float* __restrict__ ea,
    const unsigned short* __restrict__ WT1, const float* __restrict__ bc1,
    const unsigned short* __restrict__ WT2, const float* __restrict__ bc2,
    const float* __restrict__ Wc3, const float* __restrict__ bc3,
    float* __restrict__ out, int E, const int* flag) {
    __shared__ __align__(16) char smem[150528];
    unsigned short* wt1f = (unsigned short*)smem;             // 40 frags x 128 j
    unsigned short* z1b  = (unsigned short*)(smem + 81920);   // [256][134]

    const int tid = threadIdx.x;
    const int is64 = *flag;
    const int l  = tid & 63;
    const int w  = tid >> 6;    // wave 0..7
    const int lm = l & 15;
    const int g  = l >> 4;

    for (int i = tid; i < 5120; i += 512) {
        int f = i >> 7, j = i & 127;
        uint4 v = *(const uint4*)(WT1 + (size_t)j * 320 + (f >> 2) * 32 + (f & 3) * 8);
        *(uint4*)(wt1f + (size_t)i * 8) = v;
    }
    float wc3r[4];
#pragma unroll
    for (int n = 0; n < 4; ++n) wc3r[n] = Wc3[16 * n + lm];
    const float bc3s = bc3[0];
    const f32x4 zero = {0.f, 0.f, 0.f, 0.f};
    __syncthreads();   // ONLY barrier

    const int T = (E + 255) / 256;
    for (int tile = blockIdx.x; tile < T; tile += gridDim.x) {
        const int tbase = tile * 256;

        bf16x8 A[2][10];
#pragma unroll
        for (int h = 0; h < 2; ++h) {
            const int e  = tbase + 32 * w + 16 * h + lm;
            const int ec = min(e, E - 1);
            const int sE = ld_idx(ei, ec, is64);
            const int dE = ld_idx(ei, (long long)E + ec, is64);
            const unsigned short* rs = h2b + (size_t)sE * 128 + g * 8;
            const unsigned short* rd = h2b + (size_t)dE * 128 + g * 8;
#pragma unroll
            for (int kt = 0; kt < 4; ++kt) A[h][kt] = *(const bf16x8*)(rs + kt * 32);
#pragma unroll
            for (int kt = 0; kt < 4; ++kt) A[h][4 + kt] = *(const bf16x8*)(rd + kt * 32);
            const float* pe = ea + (size_t)ec * 64 + g * 8;
            float4 f0 = *(const float4*)pe,        f1 = *(const float4*)(pe + 4);
            float4 f2 = *(const float4*)(pe + 32), f3 = *(const float4*)(pe + 36);
            A[h][8] = packbf(f0, f1);
            A[h][9] = packbf(f2, f3);
        }

        f32x4 acc[2][8];
#pragma unroll
        for (int h = 0; h < 2; ++h)
#pragma unroll
            for (int n = 0; n < 8; ++n) acc[h][n] = zero;
#pragma unroll
        for (int kt = 0; kt < 10; ++kt) {
            const unsigned short* wb = wt1f + ((size_t)(kt * 4 + g) * 128) * 8;
#pragma unroll
            for (int n = 0; n < 8; ++n) {
                bf16x8 b = *(const bf16x8*)(wb + (size_t)(16 * n + lm) * 8);
                acc[0][n] = __builtin_amdgcn_mfma_f32_16x16x32_bf16(A[0][kt], b, acc[0][n], 0, 0, 0);
                acc[1][n] = __builtin_amdgcn_mfma_f32_16x16x32_bf16(A[1][kt], b, acc[1][n], 0, 0, 0);
            }
        }
#pragma unroll
        for (int n = 0; n < 8; ++n) {
            float bj = bc1[16 * n + lm];
#pragma unroll
            for (int h = 0; h < 2; ++h)
#pragma unroll
                for (int r = 0; r < 4; ++r) {
                    float v = fmaxf(acc[h][n][r] + bj, 0.f);
                    z1b[(size_t)(32 * w + 16 * h + g * 4 + r) * 134 + 16 * n + lm] = f2b(v);
                }
        }

        f32x4 acc2[2][4];
#pragma unroll
        for (int h = 0; h < 2; ++h)
#pragma unroll
            for (int n = 0; n < 4; ++n) acc2[h][n] = zero;
        const unsigned short* brow0 = z1b + (size_t)(32 * w + lm) * 134;
        const unsigned short* brow1 = z1b + (size_t)(32 * w + 16 + lm) * 134;
#pragma unroll
        for (int kt = 0; kt < 4; ++kt) {
            bf16x8 a0 = *(const bf16x8*)(brow0 + kt * 32 + g * 8);
            bf16x8 a1 = *(const bf16x8*)(brow1 + kt * 32 + g * 8);
#pragma unroll
            for (int n = 0; n < 4; ++n) {
                bf16x8 b = *(const bf16x8*)(WT2 + (size_t)(16 * n + lm) * 128 + kt * 32 + g * 8);
                acc2[0][n] = __builtin_amdgcn_mfma_f32_16x16x32_bf16(a0, b, acc2[0][n], 0, 0, 0);
                acc2[1][n] = __builtin_amdgcn_mfma_f32_16x16x32_bf16(a1, b, acc2[1][n], 0, 0, 0);
            }
        }

#pragma unroll
        for (int h = 0; h < 2; ++h) {
            float p[4];
#pragma unroll
            for (int r = 0; r < 4; ++r) p[r] = 0.f;
#pragma unroll
            for (int n = 0; n < 4; ++n) {
                float bj = bc2[16 * n + lm];
#pragma unroll
                for (int r = 0; r < 4; ++r) {
                    float z = fmaxf(acc2[h][n][r] + bj, 0.f);
                    p[r] += z * wc3r[n];
                }
            }
#pragma unroll
            for (int r = 0; r < 4; ++r) {
                p[r] += __shfl_xor(p[r], 1, 16);
                p[r] += __shfl_xor(p[r], 2, 16);
                p[r] += __shfl_xor(p[r], 4, 16);
                p[r] += __shfl_xor(p[r], 8, 16);
            }
            if (lm == 0) {
#pragma unroll
                for (int r = 0; r < 4; ++r) {
                    int eo = tbase + 32 * w + 16 * h + 4 * g + r;
                    if (eo < E) out[eo] = p[r] + bc3s;
                }
            }
        }
    }
}

extern "C" void kernel_launch(void* const* d_in, const int* in_sizes, int n_in,
                              void* d_out, int out_size, void* d_ws,
                              size_t ws_size, hipStream_t stream) {
    const float* x   = (const float*)d_in[0];
    const void*  ei  = d_in[1];
    const float* ea  = (const float*)d_in[2];
    const float* W1  = (const float*)d_in[3];
    const float* b1  = (const float*)d_in[4];
    const float* W2  = (const float*)d_in[5];
    const float* b2  = (const float*)d_in[6];
    const float* Wc1 = (const float*)d_in[7];
    const float* bc1 = (const float*)d_in[8];
    const float* Wc2 = (const float*)d_in[9];
    const float* bc2 = (const float*)d_in[10];
    const float* Wc3 = (const float*)d_in[11];
    const float* bc3 = (const float*)d_in[12];
    float* out = (float*)d_out;

    int N = in_sizes[0] / 16;   // 50000
    int E = in_sizes[2] / 64;   // 800000

    char* ws = (char*)d_ws;
    size_t off = 0;
    auto alloc = [&](size_t bytes) {
        void* p = ws + off;
        off += (bytes + 511) & ~(size_t)511;
        return p;
    };
    int*            cnt    = (int*)alloc((size_t)N * 4);
    int*            cursor = (int*)alloc((size_t)N * 4);
    int*            row    = (int*)alloc((size_t)(N + 1) * 4);
    int*            bsum   = (int*)alloc(64 * 4);
    int2*           epairs = (int2*)alloc((size_t)E * 8);
    int*            flag   = (int*)alloc(4);
    float*          agg1   = (float*)alloc((size_t)N * 80 * 4);
    unsigned short* h1b    = (unsigned short*)alloc((size_t)N * 128 * 2);
    float*          agg2   = (float*)alloc((size_t)N * 128 * 4);
    unsigned short* h2b    = (unsigned short*)alloc((size_t)N * 128 * 2);
    unsigned short* WT1    = (unsigned short*)alloc((size_t)128 * 320 * 2);
    unsigned short* WT2    = (unsigned short*)alloc((size_t)64 * 128 * 2);
    unsigned short* WU2    = (unsigned short*)alloc((size_t)128 * 320 * 2);
    unsigned short* WU1    = (unsigned short*)alloc((size_t)128 * 96 * 2);
    (void)ws_size; (void)n_in; (void)out_size;

    int nb = (N + 4095) / 4096;   // 13

    hipMemsetAsync(cnt, 0, (size_t)N * 4, stream);
    hipMemsetAsync(cursor, 0, (size_t)N * 4, stream);

    detect64_kernel<<<1, 64, 0, stream>>>(ei, flag);
    prep_w_kernel<<<160, 256, 0, stream>>>(Wc1, Wc2, W2, W1, WT1, WT2, WU2, WU1);
    hist_kernel<<<1024, 256, 0, stream>>>(ei, E, cnt, flag);
    scanA_kernel<<<nb, 1024, 0, stream>>>(cnt, bsum, N);
    scanB_kernel<<<1, 64, 0, stream>>>(bsum, nb, row, N);
    scanC_kernel<<<nb, 1024, 0, stream>>>(cnt, bsum, row, N);
    fill_kernel<<<1024, 256, 0, stream>>>(ei, E, row, cursor, epairs, flag);
    agg1_kernel<<<(N + 3) / 4, 256, 0, stream>>>(epairs, x, ea, row, agg1, N);
    update1_mfma<<<(N + 255) / 256, 512, 0, stream>>>(x, agg1, row, WU1, b1, h1b, N);
    agg2_kernel<<<(N + 3) / 4, 256, 0, stream>>>(epairs, (const unsigned int*)h1b, row, agg2, N);
    update2_mfma<<<(N + 255) / 256, 512, 0, stream>>>(h1b, agg2, agg1, row, WU2, b2, h2b, N);
    classifier_mfma<<<256, 512, 0, stream>>>(ei, h2b, ea, WT1, bc1,
                                             WT2, bc2, Wc3, bc3,
                                             out, E, flag);
}